// Round 3
// baseline (1119.417 us; speedup 1.0000x reference)
//
#include <hip/hip_runtime.h>
#include <hip/hip_bf16.h>

#define SEQ 2048
#define DIM 1024
#define NH 16
#define DK 64
#define NBH 32
#define MROWS 4096  // B*SEQ
#define BM 128
#define BN 128
#define BK 32

typedef __attribute__((ext_vector_type(8))) short bf16x8_t;  // 8 bf16 (4 VGPRs)
typedef __attribute__((ext_vector_type(4))) short bf16x4_t;  // 4 bf16 (8B)
typedef __attribute__((ext_vector_type(4))) float f32x4_t;   // MFMA accumulator

__device__ __forceinline__ unsigned short f2bf(float f) {
  union { float f; unsigned u; } v; v.f = f;
  unsigned r = v.u + 0x7FFFu + ((v.u >> 16) & 1u);  // RNE
  return (unsigned short)(r >> 16);
}

// async global->LDS, 16B per lane. Dest is wave-uniform base; HW adds lane*16.
__device__ __forceinline__ void gload16(const unsigned short* g, unsigned short* l) {
  __builtin_amdgcn_global_load_lds((const __attribute__((address_space(1))) void*)g,
                                   (__attribute__((address_space(3))) void*)l, 16, 0, 0);
}

// ---------------- f32 -> bf16 conversion of q,k,v,Wq,Wout ----------------
struct Cvt5 {
  const float* src[5];
  unsigned short* dst[5];
  int n4[5];
};

__global__ __launch_bounds__(256) void cvt5_kernel(Cvt5 P) {
  int i = blockIdx.x * 256 + threadIdx.x;
  int off = 0;
#pragma unroll
  for (int s = 0; s < 5; ++s) {
    int n4 = P.n4[s];
    int j = i - off;
    if (j >= 0 && j < n4) {
      float4 v = reinterpret_cast<const float4*>(P.src[s])[j];
      ushort4 o = make_ushort4(f2bf(v.x), f2bf(v.y), f2bf(v.z), f2bf(v.w));
      reinterpret_cast<ushort4*>(P.dst[s])[j] = o;
    }
    off += n4;
  }
}

// ---------------- mask dtype detection + normalization to bytes ----------------
__global__ void detect_mask_kernel(const unsigned int* m, int* flag) {
  unsigned acc = 0;
  for (int i = threadIdx.x; i < 2048; i += 64)  // 8KB = 2048 dwords
    acc |= (m[i] & 0xFFFFFF00u);
  unsigned long long b = __ballot(acc != 0);
  if (threadIdx.x == 0) *flag = (b != 0ull) ? 1 : 0;
}

__global__ __launch_bounds__(256) void cvt_mask_kernel(const void* msrc, unsigned char* mdst, const int* flag) {
  int i = blockIdx.x * 256 + threadIdx.x;  // 4 elements per thread
  if (*flag) {  // bool bytes
    reinterpret_cast<uchar4*>(mdst)[i] = reinterpret_cast<const uchar4*>(msrc)[i];
  } else {      // int32
    int4 v = reinterpret_cast<const int4*>(msrc)[i];
    reinterpret_cast<uchar4*>(mdst)[i] =
        make_uchar4((unsigned char)(v.x != 0), (unsigned char)(v.y != 0),
                    (unsigned char)(v.z != 0), (unsigned char)(v.w != 0));
  }
}

// ---------------- m97-style GEMM core: 128x128 tile, BK=32, 4 waves ----------------
// SWAPPED operands: acc[m][n] = mfma(W_frag, X_frag, acc) so D row-index = output
// column -> each lane owns 4 CONSECUTIVE output columns of one row (vector stores).
__device__ __forceinline__ void gemm_core_128(const unsigned short* A, const unsigned short* Wb,
                                              unsigned short* AL, unsigned short* BL,
                                              f32x4_t acc[4][4], int wv, int lane,
                                              int wr, int wc, int lr, int lg) {
  for (int k0 = 0; k0 < DIM; k0 += BK) {
    if (k0) __syncthreads();  // previous tile's reads complete before overwrite
#pragma unroll
    for (int j = 0; j < 2; ++j) {
      const int e = wv * 1024 + j * 512 + lane * 8;  // element pos in 4096-elem tile
      const int row = e >> 5, kk = e & 31;
      gload16(A + (size_t)row * DIM + k0 + kk, AL + wv * 1024 + j * 512);
      gload16(Wb + (size_t)row * DIM + k0 + kk, BL + wv * 1024 + j * 512);
    }
    __syncthreads();  // compiler drains vmcnt before barrier -> staged data ready
    bf16x8_t a[4], b[4];
#pragma unroll
    for (int m = 0; m < 4; ++m)
      a[m] = *reinterpret_cast<const bf16x8_t*>(AL + (wr * 64 + m * 16 + lr) * BK + lg * 8);
#pragma unroll
    for (int n = 0; n < 4; ++n)
      b[n] = *reinterpret_cast<const bf16x8_t*>(BL + (wc * 64 + n * 16 + lr) * BK + lg * 8);
#pragma unroll
    for (int m = 0; m < 4; ++m)
#pragma unroll
      for (int n = 0; n < 4; ++n)
        acc[m][n] = __builtin_amdgcn_mfma_f32_16x16x32_bf16(b[n], a[m], acc[m][n], 0, 0, 0);
  }
}

// ---------------- projection GEMM: C = X @ Wq^T + bq, head-split bf16 out ----------------
struct Proj3 {
  const unsigned short* A[3];
  unsigned short* dst[3];
};

__global__ __launch_bounds__(256) void proj_gemm_kernel(Proj3 P, const unsigned short* W, const float* bias) {
  const int mtile = blockIdx.x, ntile = blockIdx.y, which = blockIdx.z;
  const unsigned short* A = P.A[which] + (size_t)(mtile * BM) * DIM;
  const unsigned short* Wb = W + (size_t)(ntile * BN) * DIM;
  __shared__ __align__(16) unsigned short AL[BM * BK];
  __shared__ __align__(16) unsigned short BL[BN * BK];
  const int tid = threadIdx.x;
  const int wv = tid >> 6, lane = tid & 63;
  const int lr = lane & 15, lg = lane >> 4;
  const int wr = wv >> 1, wc = wv & 1;
  f32x4_t acc[4][4] = {};
  gemm_core_128(A, Wb, AL, BL, acc, wv, lane, wr, wc, lr, lg);

  // D[row = W-row (output col), col = X-row]: lane owns cols dfull0..+3 at row mg
  unsigned short* dst = P.dst[which];
  const int h = ntile * 2 + wc;  // head = (ntile*128 + wc*64) >> 6
#pragma unroll
  for (int m = 0; m < 4; ++m) {
    const int mg = mtile * BM + wr * 64 + m * 16 + lr;
    const int b_ = mg >> 11, s = mg & (SEQ - 1);
    unsigned short* drow = dst + ((size_t)(b_ * NH + h) * SEQ + s) * DK;
#pragma unroll
    for (int n = 0; n < 4; ++n) {
      const int d0 = n * 16 + lg * 4;                    // d within head, 4 consecutive
      const float4 bv = *reinterpret_cast<const float4*>(&bias[ntile * BN + wc * 64 + d0]);
      bf16x4_t o;
      o[0] = (short)f2bf(acc[m][n][0] + bv.x);
      o[1] = (short)f2bf(acc[m][n][1] + bv.y);
      o[2] = (short)f2bf(acc[m][n][2] + bv.z);
      o[3] = (short)f2bf(acc[m][n][3] + bv.w);
      *reinterpret_cast<bf16x4_t*>(drow + d0) = o;
    }
  }
}

// ---------------- output GEMM + bias + residual, f32 out ----------------
__global__ __launch_bounds__(256) void out_gemm_kernel(const unsigned short* Ain, const unsigned short* W,
                                                       const float* bias, const float* resid, float* X) {
  const int mtile = blockIdx.x, ntile = blockIdx.y;
  const unsigned short* A = Ain + (size_t)(mtile * BM) * DIM;
  const unsigned short* Wb = W + (size_t)(ntile * BN) * DIM;
  __shared__ __align__(16) unsigned short AL[BM * BK];
  __shared__ __align__(16) unsigned short BL[BN * BK];
  const int tid = threadIdx.x;
  const int wv = tid >> 6, lane = tid & 63;
  const int lr = lane & 15, lg = lane >> 4;
  const int wr = wv >> 1, wc = wv & 1;
  f32x4_t acc[4][4] = {};
  gemm_core_128(A, Wb, AL, BL, acc, wv, lane, wr, wc, lr, lg);

#pragma unroll
  for (int m = 0; m < 4; ++m) {
    const int mg = mtile * BM + wr * 64 + m * 16 + lr;
    float* xrow = X + (size_t)mg * DIM;
    const float* rrow = resid + (size_t)mg * DIM;
#pragma unroll
    for (int n = 0; n < 4; ++n) {
      const int c0 = ntile * BN + wc * 64 + n * 16 + lg * 4;  // 4 consecutive cols
      const float4 bv = *reinterpret_cast<const float4*>(&bias[c0]);
      const float4 rv = *reinterpret_cast<const float4*>(&rrow[c0]);
      float4 o;
      o.x = acc[m][n][0] + bv.x + rv.x;
      o.y = acc[m][n][1] + bv.y + rv.y;
      o.z = acc[m][n][2] + bv.z + rv.z;
      o.w = acc[m][n][3] + bv.w + rv.w;
      *reinterpret_cast<float4*>(&xrow[c0]) = o;
    }
  }
}

// ---------------- transpose vp [bh][s][d] -> vpT [bh][d][s] ----------------
__global__ __launch_bounds__(256) void transpose_v_kernel(const unsigned short* vp, unsigned short* vpT) {
  const int stile = blockIdx.x, bh = blockIdx.y;
  const int s0 = stile * 64;
  __shared__ unsigned short ld[64][66];  // +2 pad: conflict-free column reads
  const int t = threadIdx.x;
  const int r = t >> 2, c0 = (t & 3) * 16;
  const unsigned short* src = vp + ((size_t)bh * SEQ + s0 + r) * DK + c0;
  bf16x8_t v0 = *reinterpret_cast<const bf16x8_t*>(src);
  bf16x8_t v1 = *reinterpret_cast<const bf16x8_t*>(src + 8);
#pragma unroll
  for (int j = 0; j < 8; ++j) {
    ld[r][c0 + j] = (unsigned short)v0[j];
    ld[r][c0 + 8 + j] = (unsigned short)v1[j];
  }
  __syncthreads();
  bf16x8_t w0, w1;
#pragma unroll
  for (int j = 0; j < 8; ++j) {
    w0[j] = (short)ld[c0 + j][r];
    w1[j] = (short)ld[c0 + 8 + j][r];
  }
  unsigned short* dstp = vpT + ((size_t)bh * DK + r) * SEQ + s0 + c0;
  *reinterpret_cast<bf16x8_t*>(dstp) = w0;
  *reinterpret_cast<bf16x8_t*>(dstp + 8) = w1;
}

// ---------------- attention v3: swapped QK^T, lane-local rows, prefetch ----------------
// Lane (lr,lg) owns S^T[k = c0+lg*4+{0..3}][q = qrow0+lr]: mask = 1 uchar4 load,
// w = 1 float4 store, softmax reduce = 2 shfl_xor. PV swapped too: O^T = Vt x P^T.
__global__ __launch_bounds__(256) void attn_kernel(const unsigned short* qp, const unsigned short* kp,
                                                   const unsigned short* vpT, const unsigned char* maskb,
                                                   float* wout, unsigned short* attn_o) {
  // XCD-aware bijective swizzle: 1024 blocks, xcd = lin%8 -> 4 bh per XCD (K/V fit L2)
  const int lin = blockIdx.y * gridDim.x + blockIdx.x;
  const int xcd = lin & 7, chunk = lin >> 3;
  const int bh = xcd * 4 + (chunk & 3);
  const int qtile = chunk >> 2;
  const int wv = threadIdx.x >> 6;
  const int l = threadIdx.x & 63;
  const int lr = l & 15, lg = l >> 4;
  const int qrow0 = qtile * 64 + wv * 16;
  const unsigned short* qptr = qp + ((size_t)bh * SEQ + qrow0 + lr) * DK + lg * 8;
  const bf16x8_t bq0 = *reinterpret_cast<const bf16x8_t*>(qptr);        // Q B-frag d 0..31
  const bf16x8_t bq1 = *reinterpret_cast<const bf16x8_t*>(qptr + 32);   // d 32..63
  const int mb = bh & 1;  // tile() quirk: mask batch = (b*16+h) % 2
  const unsigned char* mrow = maskb + ((size_t)mb * SEQ + qrow0 + lr) * SEQ;  // lane's q-row
  const unsigned short* kbase = kp + (size_t)bh * SEQ * DK + lg * 8;
  const float scale = 0.03125f;  // 1/sqrt(1024)

#define LDK(c) *reinterpret_cast<const bf16x8_t*>(kbase + (size_t)((c) + lr) * DK)
#define LDK2(c) *reinterpret_cast<const bf16x8_t*>(kbase + (size_t)((c) + lr) * DK + 32)

  // ---- pass 1: row sums of exp (scores O(1): no max-subtraction needed) ----
  float sum = 0.f;
  {
    bf16x8_t kA0 = LDK(0), kA1 = LDK2(0);
    for (int c0 = 0; c0 < SEQ; c0 += 32) {
      bf16x8_t kB0 = LDK(c0 + 16), kB1 = LDK2(c0 + 16);
      {
        f32x4_t s4 = {0.f, 0.f, 0.f, 0.f};
        s4 = __builtin_amdgcn_mfma_f32_16x16x32_bf16(kA0, bq0, s4, 0, 0, 0);
        s4 = __builtin_amdgcn_mfma_f32_16x16x32_bf16(kA1, bq1, s4, 0, 0, 0);
        uchar4 mv = *reinterpret_cast<const uchar4*>(mrow + c0 + lg * 4);
        sum += (mv.x ? 0.f : __expf(s4[0] * scale)) + (mv.y ? 0.f : __expf(s4[1] * scale))
             + (mv.z ? 0.f : __expf(s4[2] * scale)) + (mv.w ? 0.f : __expf(s4[3] * scale));
      }
      const int nc = (c0 + 32) & (SEQ - 1);
      kA0 = LDK(nc); kA1 = LDK2(nc);
      {
        f32x4_t s4 = {0.f, 0.f, 0.f, 0.f};
        s4 = __builtin_amdgcn_mfma_f32_16x16x32_bf16(kB0, bq0, s4, 0, 0, 0);
        s4 = __builtin_amdgcn_mfma_f32_16x16x32_bf16(kB1, bq1, s4, 0, 0, 0);
        uchar4 mv = *reinterpret_cast<const uchar4*>(mrow + c0 + 16 + lg * 4);
        sum += (mv.x ? 0.f : __expf(s4[0] * scale)) + (mv.y ? 0.f : __expf(s4[1] * scale))
             + (mv.z ? 0.f : __expf(s4[2] * scale)) + (mv.w ? 0.f : __expf(s4[3] * scale));
      }
    }
  }
  sum += __shfl_xor(sum, 16);
  sum += __shfl_xor(sum, 32);
  const float inv = 1.f / sum;

  // ---- pass 2: recompute, write w (float4), accumulate O^T = Vt @ P^T ----
  float* wrow = wout + ((size_t)bh * SEQ + qrow0 + lr) * SEQ;  // lane's q-row in w
  const unsigned short* vbase = vpT + (size_t)bh * DK * SEQ + lg * 8;
  __shared__ __align__(16) unsigned short Plds[4][16][40];  // per-wave, pad 40: <=2-way banks
  f32x4_t o0 = {0.f, 0.f, 0.f, 0.f}, o1 = o0, o2 = o0, o3 = o0;

#define COMP(c0base, kk0, kk1, w16)                                                     \
  {                                                                                     \
    f32x4_t s4 = {0.f, 0.f, 0.f, 0.f};                                                  \
    s4 = __builtin_amdgcn_mfma_f32_16x16x32_bf16(kk0, bq0, s4, 0, 0, 0);                \
    s4 = __builtin_amdgcn_mfma_f32_16x16x32_bf16(kk1, bq1, s4, 0, 0, 0);                \
    uchar4 mv = *reinterpret_cast<const uchar4*>(mrow + (c0base) + lg * 4);             \
    float4 pv;                                                                          \
    pv.x = mv.x ? 0.f : __expf(s4[0] * scale) * inv;                                    \
    pv.y = mv.y ? 0.f : __expf(s4[1] * scale) * inv;                                    \
    pv.z = mv.z ? 0.f : __expf(s4[2] * scale) * inv;                                    \
    pv.w = mv.w ? 0.f : __expf(s4[3] * scale) * inv;                                    \
    *reinterpret_cast<float4*>(wrow + (c0base) + lg * 4) = pv;                          \
    bf16x4_t pb;                                                                        \
    pb[0] = (short)f2bf(pv.x); pb[1] = (short)f2bf(pv.y);                               \
    pb[2] = (short)f2bf(pv.z); pb[3] = (short)f2bf(pv.w);                               \
    *reinterpret_cast<bf16x4_t*>(&Plds[wv][lr][(w16) * 16 + lg * 4]) = pb;              \
  }

  {
    bf16x8_t kA0 = LDK(0), kA1 = LDK2(0);
    for (int k0 = 0; k0 < SEQ; k0 += 32) {
      // V for this 32-window, issued early (used after ~80 VALU ops)
      const bf16x8_t va0 = *reinterpret_cast<const bf16x8_t*>(vbase + (size_t)( 0 + lr) * SEQ + k0);
      const bf16x8_t va1 = *reinterpret_cast<const bf16x8_t*>(vbase + (size_t)(16 + lr) * SEQ + k0);
      const bf16x8_t va2 = *reinterpret_cast<const bf16x8_t*>(vbase + (size_t)(32 + lr) * SEQ + k0);
      const bf16x8_t va3 = *reinterpret_cast<const bf16x8_t*>(vbase + (size_t)(48 + lr) * SEQ + k0);
      bf16x8_t kB0 = LDK(k0 + 16), kB1 = LDK2(k0 + 16);
      COMP(k0, kA0, kA1, 0);
      const int nc = (k0 + 32) & (SEQ - 1);
      kA0 = LDK(nc); kA1 = LDK2(nc);
      COMP(k0 + 16, kB0, kB1, 1);
      const bf16x8_t pfrag = *reinterpret_cast<const bf16x8_t*>(&Plds[wv][lr][lg * 8]);
      o0 = __builtin_amdgcn_mfma_f32_16x16x32_bf16(va0, pfrag, o0, 0, 0, 0);
      o1 = __builtin_amdgcn_mfma_f32_16x16x32_bf16(va1, pfrag, o1, 0, 0, 0);
      o2 = __builtin_amdgcn_mfma_f32_16x16x32_bf16(va2, pfrag, o2, 0, 0, 0);
      o3 = __builtin_amdgcn_mfma_f32_16x16x32_bf16(va3, pfrag, o3, 0, 0, 0);
    }
  }
#undef COMP
#undef LDK
#undef LDK2

  // O^T[d = t*16 + lg*4 + r][q = qrow0+lr] -> attn_o[b][s][h*64+d], 8B stores
  const int b_ = bh >> 4, h = bh & 15;
  unsigned short* obase = attn_o + ((size_t)b_ * SEQ + qrow0 + lr) * DIM + h * DK + lg * 4;
  f32x4_t oacc[4] = {o0, o1, o2, o3};
#pragma unroll
  for (int t = 0; t < 4; ++t) {
    bf16x4_t ov;
    ov[0] = (short)f2bf(oacc[t][0]);
    ov[1] = (short)f2bf(oacc[t][1]);
    ov[2] = (short)f2bf(oacc[t][2]);
    ov[3] = (short)f2bf(oacc[t][3]);
    *reinterpret_cast<bf16x4_t*>(obase + t * 16) = ov;
  }
}

// ---------------- LayerNorm over DIM=1024, one block per row ----------------
__global__ __launch_bounds__(256) void ln_kernel(const float* X, const float* gamma, const float* beta, float* out) {
  const int row = blockIdx.x;
  const int t = threadIdx.x;
  float4 v = reinterpret_cast<const float4*>(X + (size_t)row * DIM)[t];
  float s1 = v.x + v.y + v.z + v.w;
  float s2 = v.x * v.x + v.y * v.y + v.z * v.z + v.w * v.w;
#pragma unroll
  for (int sh = 1; sh < 64; sh <<= 1) {
    s1 += __shfl_xor(s1, sh);
    s2 += __shfl_xor(s2, sh);
  }
  __shared__ float p1[4], p2[4];
  if ((t & 63) == 0) { p1[t >> 6] = s1; p2[t >> 6] = s2; }
  __syncthreads();
  s1 = p1[0] + p1[1] + p1[2] + p1[3];
  s2 = p2[0] + p2[1] + p2[2] + p2[3];
  const float mu = s1 * (1.f / DIM);
  const float var = s2 * (1.f / DIM) - mu * mu;
  const float rstd = rsqrtf(var + 1e-6f);
  float4 g = reinterpret_cast<const float4*>(gamma)[t];
  float4 be = reinterpret_cast<const float4*>(beta)[t];
  float4 o;
  o.x = (v.x - mu) * rstd * g.x + be.x;
  o.y = (v.y - mu) * rstd * g.y + be.y;
  o.z = (v.z - mu) * rstd * g.z + be.z;
  o.w = (v.w - mu) * rstd * g.w + be.w;
  reinterpret_cast<float4*>(out + (size_t)row * DIM)[t] = o;
}

extern "C" void kernel_launch(void* const* d_in, const int* in_sizes, int n_in,
                              void* d_out, int out_size, void* d_ws, size_t ws_size,
                              hipStream_t stream) {
  const float* q     = (const float*)d_in[0];
  const float* k     = (const float*)d_in[1];
  const float* v     = (const float*)d_in[2];
  const void*  mask  = d_in[3];
  const float* Wq    = (const float*)d_in[4];
  const float* bq    = (const float*)d_in[5];
  const float* Wout  = (const float*)d_in[6];
  const float* bout  = (const float*)d_in[7];
  const float* gamma = (const float*)d_in[8];
  const float* beta  = (const float*)d_in[9];

  float* out0 = (float*)d_out;                    // [2, 2048, 1024]
  float* wout = out0 + (size_t)2 * SEQ * DIM;     // [32, 2048, 2048]

  char* ws = (char*)d_ws;
  size_t off = 0;
  auto alloc = [&](size_t bytes) -> char* {
    char* p = ws + off;
    off += (bytes + 255) & ~(size_t)255;
    return p;
  };
  int* flag            = (int*)alloc(256);
  unsigned short* qb   = (unsigned short*)alloc((size_t)MROWS * DIM * 2);
  unsigned short* kb   = (unsigned short*)alloc((size_t)MROWS * DIM * 2);
  unsigned short* vb   = (unsigned short*)alloc((size_t)MROWS * DIM * 2);
  unsigned short* Wqb  = (unsigned short*)alloc((size_t)DIM * DIM * 2);
  unsigned short* Wob  = (unsigned short*)alloc((size_t)DIM * DIM * 2);
  unsigned short* qp   = (unsigned short*)alloc((size_t)NBH * SEQ * DK * 2);
  unsigned short* kp   = (unsigned short*)alloc((size_t)NBH * SEQ * DK * 2);
  unsigned short* vp   = (unsigned short*)alloc((size_t)NBH * SEQ * DK * 2);
  unsigned short* vpT  = (unsigned short*)alloc((size_t)NBH * SEQ * DK * 2);
  unsigned short* ao   = (unsigned short*)alloc((size_t)MROWS * DIM * 2);
  unsigned char* maskb = (unsigned char*)alloc((size_t)2 * SEQ * SEQ);
  float* X             = (float*)alloc((size_t)MROWS * DIM * 4);

  Cvt5 C;
  C.src[0] = q;    C.dst[0] = qb;  C.n4[0] = MROWS * DIM / 4;
  C.src[1] = k;    C.dst[1] = kb;  C.n4[1] = MROWS * DIM / 4;
  C.src[2] = v;    C.dst[2] = vb;  C.n4[2] = MROWS * DIM / 4;
  C.src[3] = Wq;   C.dst[3] = Wqb; C.n4[3] = DIM * DIM / 4;
  C.src[4] = Wout; C.dst[4] = Wob; C.n4[4] = DIM * DIM / 4;
  const int totalN4 = 3 * (MROWS * DIM / 4) + 2 * (DIM * DIM / 4);
  cvt5_kernel<<<(totalN4 + 255) / 256, 256, 0, stream>>>(C);

  detect_mask_kernel<<<1, 64, 0, stream>>>((const unsigned int*)mask, flag);
  cvt_mask_kernel<<<(2 * SEQ * SEQ / 4 + 255) / 256, 256, 0, stream>>>(mask, maskb, flag);

  Proj3 P;
  P.A[0] = qb; P.dst[0] = qp;
  P.A[1] = kb; P.dst[1] = kp;
  P.A[2] = vb; P.dst[2] = vp;
  proj_gemm_kernel<<<dim3(MROWS / BM, DIM / BN, 3), 256, 0, stream>>>(P, Wqb, bq);

  transpose_v_kernel<<<dim3(SEQ / 64, NBH), 256, 0, stream>>>(vp, vpT);

  attn_kernel<<<dim3(SEQ / 64, NBH), 256, 0, stream>>>(qp, kp, vpT, maskb, wout, ao);

  out_gemm_kernel<<<dim3(MROWS / BM, DIM / BN), 256, 0, stream>>>(ao, Wob, bout, q, X);

  ln_kernel<<<MROWS, 256, 0, stream>>>(X, gamma, beta, out0);
}